// Round 6
// baseline (33.100 us; speedup 1.0000x reference)
//
#include <hip/hip_runtime.h>
#include <math.h>

// Problem constants (fixed by setup_inputs): B=8, E=8, F=16, T=2048, k=32
constexpr int Bd = 8;
constexpr int Ed = 8;
constexpr int Fd = 16;
constexpr int Td = 2048;
constexpr int K  = 32;

constexpr int TG   = 16;          // t-groups per block (lanes per f)
constexpr int TPT  = 4;           // t's per thread
constexpr int TT   = TG * TPT;    // 64 t covered per block
constexpr int HALO = K - 1;       // 31
constexpr int WIN  = TT + HALO;   // 95 staged |exo| values per f
constexpr int STRIDE = 100;       // LDS row stride (mult of 4 for float4 alignment)
constexpr int NTILE  = Td / TT;   // 32 real tiles along t
constexpr int REP    = 24;        // DIAGNOSTIC: 24x redundant replicas to surface counters

typedef float f32x2 __attribute__((ext_vector_type(2)));
typedef float f32x4 __attribute__((ext_vector_type(4)));

__device__ __forceinline__ f32x2 pk_fma(f32x2 a, f32x2 b, f32x2 c) {
    return __builtin_elementwise_fma(a, b, c);
}
__device__ __forceinline__ f32x2 pk_max(f32x2 a, f32x2 b) {
    return __builtin_elementwise_max(a, b);
}

// Algebraic simplification of the reference:
//   out[b][e][f][t] = sign(q) * sum_j softmax_j(|q|*a_j) * a_j,  a_j = |exo| window
//   out[b][e][16][t] = endo[b][e][t]
// Softmax shift: union max M over va[0..34] (exact math for any shift on this
// data; validated absmax 0.0156 in R4).
__global__ __launch_bounds__(256, 4) void tca_kernel(
    const float* __restrict__ endo,
    const float* __restrict__ exo,
    const float* __restrict__ w_expand,
    const float* __restrict__ b_expand,
    float* __restrict__ out)
{
    __shared__ float a_s[Fd * STRIDE];

    const int tid  = threadIdx.x;
    const int b    = blockIdx.z;
    const int e    = blockIdx.y;
    const int tile = blockIdx.x & (NTILE - 1);
    const int rep  = blockIdx.x >> 5;          // 0..REP-1; only rep 0 stores
    const int t0   = tile * TT;

    const int f  = tid >> 4;   // 0..15
    const int tg = tid & 15;   // 0..15
    const int t  = t0 + tg * TPT;

    // independent loads issued before the barrier
    const float4 qv = *reinterpret_cast<const float4*>(&endo[(b * Ed + e) * Td + t]);
    const float wf  = w_expand[e * Fd + f];
    const float bf  = b_expand[e * Fd + f];

    // ---- stage |exo[b, :, t0-31 .. t0+63]| into LDS (zeros for t<0) ----
    {
        const float* src = &exo[(b * Fd + f) * Td + t0 - HALO];
        #pragma unroll
        for (int k = 0; k < 6; ++k) {
            const int i = tg + k * 16;
            if (i < WIN) {
                const int tt = t0 - HALO + i;
                const float v = (tt >= 0) ? src[i] : 0.f;
                a_s[f * STRIDE + i] = fabsf(v);
            }
        }
    }
    __syncthreads();

    // ---- load union window of 35 values as 18 aligned float2 pairs ----
    f32x2 vw[18];
    {
        const f32x4* base = reinterpret_cast<const f32x4*>(&a_s[f * STRIDE + tg * TPT]);
        #pragma unroll
        for (int k4 = 0; k4 < 9; ++k4) {
            const f32x4 v4 = base[k4];
            vw[2 * k4 + 0] = f32x2{v4.x, v4.y};
            vw[2 * k4 + 1] = f32x2{v4.z, v4.w};
        }
    }
    const float va1  = vw[0].y, va3 = vw[1].y;
    const float va32 = vw[16].x, va34 = vw[17].x;

    // ---- union max M over va[0..34] (vw[17].y = va[35] is garbage: excluded) ----
    f32x2 Pv = vw[0];
    #pragma unroll
    for (int k = 1; k < 17; ++k) Pv = pk_max(Pv, vw[k]);
    const float M = fmaxf(fmaxf(Pv.x, Pv.y), va34);

    constexpr float LOG2E = 1.44269504088896340736f;
    const float qa[4] = {qv.x, qv.y, qv.z, qv.w};
    float res[4];

    #pragma unroll
    for (int p = 0; p < TPT; ++p) {
        const float q  = fmaf(qa[p], wf, bf);
        const float aq = fabsf(q);
        const float c1 = aq * LOG2E;          // exp(aq*(a-M)) == exp2(a*c1 + c0)
        const float c0 = -M * c1;
        const f32x2 c1v = {c1, c1};
        const f32x2 c0v = {c0, c0};

        f32x2 den_a = {0.f, 0.f}, den_b = {0.f, 0.f};
        f32x2 num_a = {0.f, 0.f}, num_b = {0.f, 0.f};
        float den_s = 0.f, num_s = 0.f;

        // aligned-pair ranges per p: p0 -> vw[0..15], p1 -> vw[1..15]+edges,
        // p2 -> vw[1..16], p3 -> vw[2..16]+edges  (fully inlined, const idx)
        if (p == 0) {
            #pragma unroll
            for (int k = 0; k < 16; ++k) {
                const f32x2 a = vw[k];
                const f32x2 x = pk_fma(a, c1v, c0v);
                f32x2 ev; ev.x = __builtin_amdgcn_exp2f(x.x); ev.y = __builtin_amdgcn_exp2f(x.y);
                if (k & 1) { den_b += ev; num_b = pk_fma(ev, a, num_b); }
                else       { den_a += ev; num_a = pk_fma(ev, a, num_a); }
            }
        } else if (p == 1) {
            #pragma unroll
            for (int k = 1; k < 16; ++k) {
                const f32x2 a = vw[k];
                const f32x2 x = pk_fma(a, c1v, c0v);
                f32x2 ev; ev.x = __builtin_amdgcn_exp2f(x.x); ev.y = __builtin_amdgcn_exp2f(x.y);
                if (k & 1) { den_b += ev; num_b = pk_fma(ev, a, num_b); }
                else       { den_a += ev; num_a = pk_fma(ev, a, num_a); }
            }
            const float e0 = __builtin_amdgcn_exp2f(fmaf(va1,  c1, c0));
            const float e1 = __builtin_amdgcn_exp2f(fmaf(va32, c1, c0));
            den_s = e0 + e1;
            num_s = fmaf(e0, va1, e1 * va32);
        } else if (p == 2) {
            #pragma unroll
            for (int k = 1; k < 17; ++k) {
                const f32x2 a = vw[k];
                const f32x2 x = pk_fma(a, c1v, c0v);
                f32x2 ev; ev.x = __builtin_amdgcn_exp2f(x.x); ev.y = __builtin_amdgcn_exp2f(x.y);
                if (k & 1) { den_b += ev; num_b = pk_fma(ev, a, num_b); }
                else       { den_a += ev; num_a = pk_fma(ev, a, num_a); }
            }
        } else {
            #pragma unroll
            for (int k = 2; k < 17; ++k) {
                const f32x2 a = vw[k];
                const f32x2 x = pk_fma(a, c1v, c0v);
                f32x2 ev; ev.x = __builtin_amdgcn_exp2f(x.x); ev.y = __builtin_amdgcn_exp2f(x.y);
                if (k & 1) { den_b += ev; num_b = pk_fma(ev, a, num_b); }
                else       { den_a += ev; num_a = pk_fma(ev, a, num_a); }
            }
            const float e0 = __builtin_amdgcn_exp2f(fmaf(va3,  c1, c0));
            const float e1 = __builtin_amdgcn_exp2f(fmaf(va34, c1, c0));
            den_s = e0 + e1;
            num_s = fmaf(e0, va3, e1 * va34);
        }

        const f32x2 denv = den_a + den_b;
        const f32x2 numv = num_a + num_b;
        const float den = denv.x + denv.y + den_s;   // >= 1 (max term -> exp2(~0)=1)
        const float num = numv.x + numv.y + num_s;
        const float s = (q > 0.f) ? 1.f : ((q < 0.f) ? -1.f : 0.f);
        res[p] = s * num * __builtin_amdgcn_rcpf(den);
    }

    // only replica 0 stores (runtime-uniform branch; replicas still execute
    // the full compute above -- instruction stream identical across blocks)
    if (rep == 0) {
        if (f == 0) {
            *reinterpret_cast<float4*>(
                &out[(((b * Ed + e) * (Fd + 1)) + Fd) * Td + t]) = qv;
        }
        const float4 r = make_float4(res[0], res[1], res[2], res[3]);
        *reinterpret_cast<float4*>(
            &out[(((b * Ed + e) * (Fd + 1)) + f) * Td + t]) = r;
    }
}

extern "C" void kernel_launch(void* const* d_in, const int* in_sizes, int n_in,
                              void* d_out, int out_size, void* d_ws, size_t ws_size,
                              hipStream_t stream) {
    const float* endo = (const float*)d_in[0];
    const float* exo  = (const float*)d_in[1];
    const float* w    = (const float*)d_in[2];
    const float* bb   = (const float*)d_in[3];
    float* out = (float*)d_out;

    dim3 grid(NTILE * REP, Ed, Bd);   // (768, 8, 8) = 49152 blocks, 24x redundant
    tca_kernel<<<grid, 256, 0, stream>>>(endo, exo, w, bb, out);
}

// Round 7
// 16.343 us; speedup vs baseline: 2.0254x; 2.0254x over previous
//
#include <hip/hip_runtime.h>
#include <math.h>

// Problem constants (fixed by setup_inputs): B=8, E=8, F=16, T=2048, k=32
constexpr int Bd = 8;
constexpr int Ed = 8;
constexpr int Fd = 16;
constexpr int Td = 2048;
constexpr int K  = 32;

constexpr int TG   = 16;          // t-groups per block (lanes per f)
constexpr int TPT  = 4;           // t's per thread
constexpr int TT   = TG * TPT;    // 64 t covered per block
constexpr int HALO = K - 1;       // 31
constexpr int WIN  = TT + HALO;   // 95 staged |exo| values per f
constexpr int STRIDE = 100;       // LDS row stride (mult of 4 for float4 alignment)

typedef float f32x2 __attribute__((ext_vector_type(2)));
typedef float f32x4 __attribute__((ext_vector_type(4)));

__device__ __forceinline__ f32x2 pk_fma(f32x2 a, f32x2 b, f32x2 c) {
    return __builtin_elementwise_fma(a, b, c);
}
__device__ __forceinline__ f32x2 pk_max(f32x2 a, f32x2 b) {
    return __builtin_elementwise_max(a, b);
}

// Algebraic simplification of the reference:
//   product = q*kv; |product| = |q|*|kv|; sign(product)*kv = sign(q)*|kv|
//   out[b][e][f][t] = sign(q) * sum_j softmax_j(|q|*a_j) * a_j,  a_j = |exo| window
//   out[b][e][16][t] = endo[b][e][t]
// Softmax shift: union max M over va[0..34] (exact math for any shift).
//
// Measured (R6 diagnostic, 24x replicated): kernel is v_exp_f32
// trans-pipe-bound at 64 lanes/cyc/CU; per-copy compute ~1.7 us. The
// remaining measured dur_us is fixed launch/graph overhead (~15 us).
__global__ __launch_bounds__(256, 4) void tca_kernel(
    const float* __restrict__ endo,
    const float* __restrict__ exo,
    const float* __restrict__ w_expand,
    const float* __restrict__ b_expand,
    float* __restrict__ out)
{
    __shared__ float a_s[Fd * STRIDE];

    const int tid = threadIdx.x;
    const int b   = blockIdx.z;
    const int e   = blockIdx.y;
    const int t0  = blockIdx.x * TT;

    const int f  = tid >> 4;   // 0..15
    const int tg = tid & 15;   // 0..15
    const int t  = t0 + tg * TPT;

    // independent loads issued before the barrier
    const float4 qv = *reinterpret_cast<const float4*>(&endo[(b * Ed + e) * Td + t]);
    const float wf  = w_expand[e * Fd + f];
    const float bf  = b_expand[e * Fd + f];

    // ---- stage |exo[b, :, t0-31 .. t0+63]| into LDS (zeros for t<0) ----
    {
        const float* src = &exo[(b * Fd + f) * Td + t0 - HALO];
        #pragma unroll
        for (int k = 0; k < 6; ++k) {
            const int i = tg + k * 16;
            if (i < WIN) {
                const int tt = t0 - HALO + i;
                const float v = (tt >= 0) ? src[i] : 0.f;
                a_s[f * STRIDE + i] = fabsf(v);
            }
        }
    }
    __syncthreads();

    // passthrough channel (slot 16)
    if (f == 0) {
        *reinterpret_cast<float4*>(
            &out[(((b * Ed + e) * (Fd + 1)) + Fd) * Td + t]) = qv;
    }

    // ---- load union window of 35 values as 18 aligned float2 pairs ----
    f32x2 vw[18];
    {
        const f32x4* base = reinterpret_cast<const f32x4*>(&a_s[f * STRIDE + tg * TPT]);
        #pragma unroll
        for (int k4 = 0; k4 < 9; ++k4) {
            const f32x4 v4 = base[k4];
            vw[2 * k4 + 0] = f32x2{v4.x, v4.y};
            vw[2 * k4 + 1] = f32x2{v4.z, v4.w};
        }
    }
    const float va1  = vw[0].y, va3 = vw[1].y;
    const float va32 = vw[16].x, va34 = vw[17].x;

    // ---- union max M over va[0..34] (vw[17].y = va[35] is garbage: excluded) ----
    f32x2 Pv = vw[0];
    #pragma unroll
    for (int k = 1; k < 17; ++k) Pv = pk_max(Pv, vw[k]);
    const float M = fmaxf(fmaxf(Pv.x, Pv.y), va34);

    constexpr float LOG2E = 1.44269504088896340736f;
    const float qa[4] = {qv.x, qv.y, qv.z, qv.w};
    float res[4];

    #pragma unroll
    for (int p = 0; p < TPT; ++p) {
        const float q  = fmaf(qa[p], wf, bf);
        const float aq = fabsf(q);
        const float c1 = aq * LOG2E;          // exp(aq*(a-M)) == exp2(a*c1 + c0)
        const float c0 = -M * c1;
        const f32x2 c1v = {c1, c1};
        const f32x2 c0v = {c0, c0};

        f32x2 den_a = {0.f, 0.f}, den_b = {0.f, 0.f};
        f32x2 num_a = {0.f, 0.f}, num_b = {0.f, 0.f};
        float den_s = 0.f, num_s = 0.f;

        // aligned-pair ranges per p: p0 -> vw[0..15], p1 -> vw[1..15]+edges,
        // p2 -> vw[1..16], p3 -> vw[2..16]+edges  (fully inlined, const idx)
        if (p == 0) {
            #pragma unroll
            for (int k = 0; k < 16; ++k) {
                const f32x2 a = vw[k];
                const f32x2 x = pk_fma(a, c1v, c0v);
                f32x2 ev; ev.x = __builtin_amdgcn_exp2f(x.x); ev.y = __builtin_amdgcn_exp2f(x.y);
                if (k & 1) { den_b += ev; num_b = pk_fma(ev, a, num_b); }
                else       { den_a += ev; num_a = pk_fma(ev, a, num_a); }
            }
        } else if (p == 1) {
            #pragma unroll
            for (int k = 1; k < 16; ++k) {
                const f32x2 a = vw[k];
                const f32x2 x = pk_fma(a, c1v, c0v);
                f32x2 ev; ev.x = __builtin_amdgcn_exp2f(x.x); ev.y = __builtin_amdgcn_exp2f(x.y);
                if (k & 1) { den_b += ev; num_b = pk_fma(ev, a, num_b); }
                else       { den_a += ev; num_a = pk_fma(ev, a, num_a); }
            }
            const float e0 = __builtin_amdgcn_exp2f(fmaf(va1,  c1, c0));
            const float e1 = __builtin_amdgcn_exp2f(fmaf(va32, c1, c0));
            den_s = e0 + e1;
            num_s = fmaf(e0, va1, e1 * va32);
        } else if (p == 2) {
            #pragma unroll
            for (int k = 1; k < 17; ++k) {
                const f32x2 a = vw[k];
                const f32x2 x = pk_fma(a, c1v, c0v);
                f32x2 ev; ev.x = __builtin_amdgcn_exp2f(x.x); ev.y = __builtin_amdgcn_exp2f(x.y);
                if (k & 1) { den_b += ev; num_b = pk_fma(ev, a, num_b); }
                else       { den_a += ev; num_a = pk_fma(ev, a, num_a); }
            }
        } else {
            #pragma unroll
            for (int k = 2; k < 17; ++k) {
                const f32x2 a = vw[k];
                const f32x2 x = pk_fma(a, c1v, c0v);
                f32x2 ev; ev.x = __builtin_amdgcn_exp2f(x.x); ev.y = __builtin_amdgcn_exp2f(x.y);
                if (k & 1) { den_b += ev; num_b = pk_fma(ev, a, num_b); }
                else       { den_a += ev; num_a = pk_fma(ev, a, num_a); }
            }
            const float e0 = __builtin_amdgcn_exp2f(fmaf(va3,  c1, c0));
            const float e1 = __builtin_amdgcn_exp2f(fmaf(va34, c1, c0));
            den_s = e0 + e1;
            num_s = fmaf(e0, va3, e1 * va34);
        }

        const f32x2 denv = den_a + den_b;
        const f32x2 numv = num_a + num_b;
        const float den = denv.x + denv.y + den_s;   // >= 1 (max term -> exp2(~0)=1)
        const float num = numv.x + numv.y + num_s;
        const float s = (q > 0.f) ? 1.f : ((q < 0.f) ? -1.f : 0.f);
        res[p] = s * num * __builtin_amdgcn_rcpf(den);
    }

    const float4 r = make_float4(res[0], res[1], res[2], res[3]);
    *reinterpret_cast<float4*>(
        &out[(((b * Ed + e) * (Fd + 1)) + f) * Td + t]) = r;
}

extern "C" void kernel_launch(void* const* d_in, const int* in_sizes, int n_in,
                              void* d_out, int out_size, void* d_ws, size_t ws_size,
                              hipStream_t stream) {
    const float* endo = (const float*)d_in[0];
    const float* exo  = (const float*)d_in[1];
    const float* w    = (const float*)d_in[2];
    const float* bb   = (const float*)d_in[3];
    float* out = (float*)d_out;

    dim3 grid(Td / TT, Ed, Bd);   // (32, 8, 8) = 2048 blocks
    tca_kernel<<<grid, 256, 0, stream>>>(endo, exo, w, bb, out);
}